// Round 9
// baseline (381.648 us; speedup 1.0000x reference)
//
#include <hip/hip_runtime.h>
#include <hip/hip_cooperative_groups.h>
#include <cstdint>

namespace cg = cooperative_groups;

#define N_T 1024
#define M_V 50000
#define DIMS 256
#define NPAD 50048
#define GPANELS 391         // 50048 / 128
#define CBLK 196            // ceil(50000/256)
#define NPART (CBLK * 64)
#define NCHUNK 782          // coop colpass chunks (gated path)
#define J8TOT 6250          // 50000/8 columns-of-8
#define J8SUB8 782          // ceil(6250/8) j8-range per column-subrange
#define F8BLK 25            // ceil(6250/256) (split-path specfinal)
#define LPART (F8BLK * 64)

constexpr float ALPHA     = 0.05f;
constexpr float INV_ALPHA = 20.0f;
constexpr float A_VAL     = 1.0f / 1024.0f;
constexpr float B_VAL     = 1.0f / 50000.0f;
constexpr float THR       = 0.005f;
constexpr float EPSV      = 1e-16f;

typedef short    bf16x8 __attribute__((ext_vector_type(8)));
typedef float    f32x4  __attribute__((ext_vector_type(4)));
typedef _Float16 half8v __attribute__((ext_vector_type(8)));

__device__ __forceinline__ float blockReduce256(float val) {
  #pragma unroll
  for (int off = 32; off; off >>= 1) val += __shfl_down(val, off, 64);
  __shared__ float redw[4];
  int lane = threadIdx.x & 63;
  int wid  = threadIdx.x >> 6;
  if (lane == 0) redw[wid] = val;
  __syncthreads();
  float r = 0.0f;
  if (threadIdx.x == 0) r = redw[0] + redw[1] + redw[2] + redw[3];
  __syncthreads();
  return r;
}

__device__ __forceinline__ unsigned short f2bf(float f) {
  union { float f; unsigned u; } c{f};
  unsigned r = c.u + 0x7FFF + ((c.u >> 16) & 1);   // RNE
  return (unsigned short)(r >> 16);
}
__device__ __forceinline__ float bf2f(unsigned short b) {
  union { unsigned u; float f; } c{(unsigned)b << 16};
  return c.f;
}

__device__ __forceinline__ void gload16(const void* g, void* l) {
  __builtin_amdgcn_global_load_lds((const __attribute__((address_space(1))) unsigned int*)g,
                                   (__attribute__((address_space(3))) unsigned int*)l, 16, 0, 0);
}

// ---- fused pack: blocks [0,512) pack x -> A'=[xh|xl]+xx; rest pack y -> B'=[yh]+yy ----
__global__ __launch_bounds__(256) void pack_kernel(const float* __restrict__ x,
                                                   const float* __restrict__ y,
                                                   unsigned short* __restrict__ Ap,
                                                   unsigned short* __restrict__ Bp,
                                                   float* __restrict__ xx,
                                                   float* __restrict__ yy) {
  __shared__ float rr[4];
  int lane = threadIdx.x & 63, wid = threadIdx.x >> 6;
  if (blockIdx.x < N_T / 2) {
    int r = blockIdx.x * 2 + (threadIdx.x >> 7);
    int k = (threadIdx.x & 127) * 2;
    float2 vx = *(const float2*)&x[(size_t)r * DIMS + k];
    ushort2 h2, l2;
    h2.x = f2bf(vx.x); h2.y = f2bf(vx.y);
    l2.x = f2bf(vx.x - bf2f(h2.x)); l2.y = f2bf(vx.y - bf2f(h2.y));
    *(ushort2*)&Ap[(size_t)r * 512 + k]       = h2;
    *(ushort2*)&Ap[(size_t)r * 512 + 256 + k] = l2;
    float ssq = vx.x * vx.x + vx.y * vx.y;
    #pragma unroll
    for (int off = 32; off; off >>= 1) ssq += __shfl_down(ssq, off, 64);
    if (lane == 0) rr[wid] = ssq;
    __syncthreads();
    if ((threadIdx.x & 127) == 0) xx[r] = rr[wid] + rr[wid + 1];
  } else {
    int r = (blockIdx.x - N_T / 2) * 2 + (threadIdx.x >> 7);
    int k = (threadIdx.x & 127) * 2;
    ushort2 h2 = {0, 0};
    float ssq = 0.0f;
    if (r < M_V) {
      float2 vy = *(const float2*)&y[(size_t)r * DIMS + k];
      h2.x = f2bf(vy.x); h2.y = f2bf(vy.y);
      ssq = vy.x * vy.x + vy.y * vy.y;
    }
    *(ushort2*)&Bp[(size_t)r * 256 + k] = h2;
    #pragma unroll
    for (int off = 32; off; off >>= 1) ssq += __shfl_down(ssq, off, 64);
    if (lane == 0) rr[wid] = ssq;
    __syncthreads();
    if ((threadIdx.x & 127) == 0 && r < M_V) yy[r] = rr[wid] + rr[wid + 1];
  }
}

// ---- MFMA GEMM -> f16 K + fused column-sum partials (2-phase dbuf, vmcnt(6)) ----
__global__ __launch_bounds__(256) void mfma_gemm_kernel(const unsigned short* __restrict__ Ap,
                                                        const unsigned short* __restrict__ Bp,
                                                        const float* __restrict__ xx,
                                                        const float* __restrict__ yy,
                                                        _Float16* __restrict__ Kh,
                                                        float* __restrict__ colsumPart) {
  const int t  = blockIdx.x & 63;
  const int gb = blockIdx.x >> 6;
  const int panel = gb * 8 + (t & 7);
  const int rt    = t >> 3;
  if (panel >= GPANELS) return;
  const int i0 = rt * 128;
  const int j0 = panel * 128;

  __shared__ unsigned short Ah[2][128][32];
  __shared__ unsigned short Al[2][128][32];
  __shared__ unsigned short Bs[2][128][32];
  const int tid  = threadIdx.x;
  const int lane = tid & 63;
  const int wid  = tid >> 6;
  const int wr = wid >> 1, wc = wid & 1;

  f32x4 acc[4][4];
  #pragma unroll
  for (int m = 0; m < 4; ++m)
    #pragma unroll
    for (int n = 0; n < 4; ++n) acc[m][n] = (f32x4){0.f, 0.f, 0.f, 0.f};

  const int srow  = lane >> 2;
  const int sslot = lane & 3;

  auto STAGE = [&](int b, int k0) {
    #pragma unroll
    for (int q = 0; q < 2; ++q) {
      int rbase = (wid * 2 + q) * 16;
      int row = rbase + srow;
      int cg_ = sslot ^ ((row >> 1) & 3);
      gload16(Ap + (size_t)(i0 + row) * 512 + k0 + cg_ * 8,       &Ah[b][rbase][0]);
      gload16(Ap + (size_t)(i0 + row) * 512 + 256 + k0 + cg_ * 8, &Al[b][rbase][0]);
      gload16(Bp + (size_t)(j0 + row) * 256 + k0 + cg_ * 8,       &Bs[b][rbase][0]);
    }
  };

  STAGE(0, 0);
  int cur = 0;
  #pragma unroll
  for (int step = 0; step < 8; ++step) {
    if (step < 7) {
      STAGE(cur ^ 1, (step + 1) * 32);
      asm volatile("s_waitcnt vmcnt(6)" ::: "memory");
    } else {
      asm volatile("s_waitcnt vmcnt(0)" ::: "memory");
    }
    __builtin_amdgcn_s_barrier();
    __builtin_amdgcn_sched_barrier(0);
    bf16x8 ah[4], al[4], bb[4];
    #pragma unroll
    for (int m = 0; m < 4; ++m) {
      int row = wr * 64 + m * 16 + (lane & 15);
      int sl  = (lane >> 4) ^ ((row >> 1) & 3);
      ah[m] = *(const bf16x8*)&Ah[cur][row][sl * 8];
      al[m] = *(const bf16x8*)&Al[cur][row][sl * 8];
    }
    #pragma unroll
    for (int n = 0; n < 4; ++n) {
      int col = wc * 64 + n * 16 + (lane & 15);
      int sl  = (lane >> 4) ^ ((col >> 1) & 3);
      bb[n] = *(const bf16x8*)&Bs[cur][col][sl * 8];
    }
    #pragma unroll
    for (int m = 0; m < 4; ++m)
      #pragma unroll
      for (int n = 0; n < 4; ++n) {
        acc[m][n] = __builtin_amdgcn_mfma_f32_16x16x32_bf16(ah[m], bb[n], acc[m][n], 0, 0, 0);
        acc[m][n] = __builtin_amdgcn_mfma_f32_16x16x32_bf16(al[m], bb[n], acc[m][n], 0, 0, 0);
      }
    asm volatile("s_waitcnt lgkmcnt(0)" ::: "memory");
    __builtin_amdgcn_sched_barrier(0);
    __builtin_amdgcn_s_barrier();
    cur ^= 1;
  }

  float csum[4] = {0.f, 0.f, 0.f, 0.f};
  #pragma unroll
  for (int m = 0; m < 4; ++m) {
    int rowb = i0 + wr * 64 + m * 16 + (lane >> 4) * 4;
    #pragma unroll
    for (int n = 0; n < 4; ++n) {
      int col = j0 + wc * 64 + n * 16 + (lane & 15);
      float yyc = (col < M_V) ? yy[col] : 0.0f;
      #pragma unroll
      for (int r = 0; r < 4; ++r) {
        float mval = xx[rowb + r] + yyc - 2.0f * acc[m][n][r];
        _Float16 kh = (_Float16)__expf(-ALPHA * mval);
        if (col < M_V) Kh[(size_t)(rowb + r) * M_V + col] = kh;
        csum[n] += (float)kh;
      }
    }
  }
  #pragma unroll
  for (int n = 0; n < 4; ++n) {
    float c = csum[n];
    c += __shfl_xor(c, 16, 64);
    c += __shfl_xor(c, 32, 64);
    if (lane < 16) {
      int col = j0 + wc * 64 + n * 16 + lane;
      colsumPart[(size_t)(rt * 2 + wr) * NPAD + col] = c;
    }
  }
}

// ---- mega_lite: phases A-D only, fully grid-size-agnostic ----
__global__ __launch_bounds__(256) void mega_lite(const _Float16* __restrict__ Kh,
                                                 const float* __restrict__ colsumPart,
                                                 float* __restrict__ u,
                                                 float* __restrict__ v,
                                                 float* errAcc,
                                                 float* __restrict__ lossPart,
                                                 float* __restrict__ sPart,
                                                 float* out,
                                                 int* notconv) {
  cg::grid_group grid = cg::this_grid();
  const int tid = threadIdx.x;
  const int bid = blockIdx.x;
  const int nb  = gridDim.x;
  const int stride = nb * 256;

  // A: v1 = b / (colsum * a + eps); zero errAcc
  for (int j = bid * 256 + tid; j < M_V; j += stride) {
    float sum = 0.0f;
    #pragma unroll
    for (int q = 0; q < 16; ++q) sum += colsumPart[(size_t)q * NPAD + j];
    v[j] = B_VAL / (sum * A_VAL + EPSV);
  }
  if (bid == 0 && tid < 4) errAcc[tid] = 0.0f;
  grid.sync();

  // B: rowpass u_i = a / (K v)_i
  for (int row = bid; row < N_T; row += nb) {
    const half8v* K8 = (const half8v*)(Kh + (size_t)row * M_V);
    const float4* v4 = (const float4*)v;
    float p = 0.0f;
    int q = tid;
    #pragma unroll
    for (int it = 0; it < 24; ++it, q += 256) {
      half8v k8 = K8[q];
      float4 va = v4[q * 2], vb = v4[q * 2 + 1];
      p += (float)k8[0] * va.x + (float)k8[1] * va.y + (float)k8[2] * va.z + (float)k8[3] * va.w
         + (float)k8[4] * vb.x + (float)k8[5] * vb.y + (float)k8[6] * vb.z + (float)k8[7] * vb.w;
    }
    if (q < J8TOT) {
      half8v k8 = K8[q];
      float4 va = v4[q * 2], vb = v4[q * 2 + 1];
      p += (float)k8[0] * va.x + (float)k8[1] * va.y + (float)k8[2] * va.z + (float)k8[3] * va.w
         + (float)k8[4] * vb.x + (float)k8[5] * vb.y + (float)k8[6] * vb.z + (float)k8[7] * vb.w;
    }
    p = blockReduce256(p);
    if (tid == 0) u[row] = A_VAL / (p + EPSV);
  }
  grid.sync();

  // C: transp (nt-stores) + loss partials + s partials; 512 work items
  {
    float contrib = 0.0f;
    for (int item = bid; item < 512; item += nb) {
      const int by = item & 63;
      const int sub = item >> 6;
      const int lo = sub * J8SUB8;
      const int hi = min(lo + J8SUB8, J8TOT);
      for (int j8 = lo + tid; j8 < hi; j8 += 256) {
        const size_t jb = (size_t)j8 * 8;
        float4 va = ((const float4*)v)[j8 * 2];
        float4 vb = ((const float4*)v)[j8 * 2 + 1];
        float sp0 = 0.f, sp1 = 0.f, sp2 = 0.f, sp3 = 0.f;
        float sp4 = 0.f, sp5 = 0.f, sp6 = 0.f, sp7 = 0.f;
        #pragma unroll
        for (int r = 0; r < 16; ++r) {
          int i = by * 16 + r;
          half8v k8 = *(const half8v*)(Kh + (size_t)i * M_V + jb);
          float ui = u[i];
          float k0 = (float)k8[0], k1 = (float)k8[1], k2 = (float)k8[2], k3 = (float)k8[3];
          float k4 = (float)k8[4], k5 = (float)k8[5], k6 = (float)k8[6], k7 = (float)k8[7];
          float t0 = ui * k0 * va.x, t1 = ui * k1 * va.y, t2 = ui * k2 * va.z, t3 = ui * k3 * va.w;
          float t4 = ui * k4 * vb.x, t5 = ui * k5 * vb.y, t6 = ui * k6 * vb.z, t7 = ui * k7 * vb.w;
          float* o = out + 1 + (size_t)i * M_V + jb;
          __builtin_nontemporal_store(t0, o);     __builtin_nontemporal_store(t1, o + 1);
          __builtin_nontemporal_store(t2, o + 2); __builtin_nontemporal_store(t3, o + 3);
          __builtin_nontemporal_store(t4, o + 4); __builtin_nontemporal_store(t5, o + 5);
          __builtin_nontemporal_store(t6, o + 6); __builtin_nontemporal_store(t7, o + 7);
          contrib += t0 * (-__logf(k0)) + t1 * (-__logf(k1)) + t2 * (-__logf(k2)) + t3 * (-__logf(k3))
                   + t4 * (-__logf(k4)) + t5 * (-__logf(k5)) + t6 * (-__logf(k6)) + t7 * (-__logf(k7));
          sp0 += k0 * ui; sp1 += k1 * ui; sp2 += k2 * ui; sp3 += k3 * ui;
          sp4 += k4 * ui; sp5 += k5 * ui; sp6 += k6 * ui; sp7 += k7 * ui;
        }
        float* sb = sPart + (size_t)by * M_V + jb;
        *(float4*)sb       = make_float4(sp0, sp1, sp2, sp3);
        *(float4*)(sb + 4) = make_float4(sp4, sp5, sp6, sp7);
      }
    }
    contrib = blockReduce256(contrib) * INV_ALPHA;
    if (tid == 0) lossPart[bid] = contrib;
  }
  grid.sync();

  // D: err = sum_j |v_j s_j - b|
  {
    float e = 0.0f;
    for (int j = bid * 256 + tid; j < M_V; j += stride) {
      float ss = 0.0f;
      #pragma unroll
      for (int q = 0; q < 64; ++q) ss += sPart[(size_t)q * M_V + j];
      e += fabsf(v[j] * ss - B_VAL);
    }
    e = blockReduce256(e);
    if (tid == 0) atomicAdd(&errAcc[0], e);
  }
  grid.sync();

  // loss total + convergence flag (block 0)
  if (bid == 0) {
    float ls = 0.0f;
    for (int i = tid; i < nb; i += 256) ls += lossPart[i];
    ls = blockReduce256(ls);
    if (tid == 0) {
      out[0] = ls;
      *notconv = (errAcc[0] > THR) ? 1 : 0;
    }
  }
}

// ---- split-path kernels (round-6 proven) ----
__global__ __launch_bounds__(256) void v1_kernel(const float* __restrict__ cp,
                                                 float* __restrict__ v,
                                                 float* __restrict__ errAcc) {
  int j = blockIdx.x * 256 + threadIdx.x;
  if (j == 0) errAcc[0] = 0.0f;
  if (j < M_V) {
    float s = 0.0f;
    #pragma unroll
    for (int q = 0; q < 16; ++q) s += cp[(size_t)q * NPAD + j];
    v[j] = B_VAL / (s * A_VAL + EPSV);
  }
}

__global__ __launch_bounds__(256) void rowpass_kernel(const _Float16* __restrict__ Kh,
                                                      const float* __restrict__ v,
                                                      float* __restrict__ rowPart) {
  const int i = blockIdx.y;
  const int c = blockIdx.x;  // 0 or 1
  const half8v* K8 = (const half8v*)(Kh + (size_t)i * M_V);
  const float4* v4 = (const float4*)v;
  float p = 0.0f;
  int q = c * 3125 + threadIdx.x;
  #pragma unroll
  for (int it = 0; it < 12; ++it, q += 256) {
    half8v k8 = K8[q];
    float4 va = v4[q * 2], vb = v4[q * 2 + 1];
    p += (float)k8[0] * va.x + (float)k8[1] * va.y + (float)k8[2] * va.z + (float)k8[3] * va.w
       + (float)k8[4] * vb.x + (float)k8[5] * vb.y + (float)k8[6] * vb.z + (float)k8[7] * vb.w;
  }
  if (threadIdx.x < 53) {
    int q2 = c * 3125 + 3072 + threadIdx.x;
    half8v k8 = K8[q2];
    float4 va = v4[q2 * 2], vb = v4[q2 * 2 + 1];
    p += (float)k8[0] * va.x + (float)k8[1] * va.y + (float)k8[2] * va.z + (float)k8[3] * va.w
       + (float)k8[4] * vb.x + (float)k8[5] * vb.y + (float)k8[6] * vb.z + (float)k8[7] * vb.w;
  }
  p = blockReduce256(p);
  if (threadIdx.x == 0) rowPart[c * N_T + i] = p;
}

__global__ void u_kernel(const float* __restrict__ rowPart, float* __restrict__ u) {
  int i = blockIdx.x * 256 + threadIdx.x;
  u[i] = A_VAL / (rowPart[i] + rowPart[N_T + i] + EPSV);
}

__global__ __launch_bounds__(256) void specfinal_kernel(const _Float16* __restrict__ Kh,
                                                        const float* __restrict__ u_,
                                                        const float* __restrict__ v_,
                                                        float* __restrict__ out,
                                                        float* __restrict__ sPart,
                                                        float* __restrict__ lossPart) {
  const int j8 = blockIdx.x * 256 + threadIdx.x;
  const int by = blockIdx.y;
  float contrib = 0.0f;
  if (j8 < J8TOT) {
    const size_t jb = (size_t)j8 * 8;
    float4 va = ((const float4*)v_)[j8 * 2];
    float4 vb = ((const float4*)v_)[j8 * 2 + 1];
    float sp0 = 0.f, sp1 = 0.f, sp2 = 0.f, sp3 = 0.f;
    float sp4 = 0.f, sp5 = 0.f, sp6 = 0.f, sp7 = 0.f;
    #pragma unroll
    for (int r = 0; r < 16; ++r) {
      int i = by * 16 + r;
      half8v k8 = *(const half8v*)(Kh + (size_t)i * M_V + jb);
      float ui = u_[i];
      float k0 = (float)k8[0], k1 = (float)k8[1], k2 = (float)k8[2], k3 = (float)k8[3];
      float k4 = (float)k8[4], k5 = (float)k8[5], k6 = (float)k8[6], k7 = (float)k8[7];
      float t0 = ui * k0 * va.x, t1 = ui * k1 * va.y, t2 = ui * k2 * va.z, t3 = ui * k3 * va.w;
      float t4 = ui * k4 * vb.x, t5 = ui * k5 * vb.y, t6 = ui * k6 * vb.z, t7 = ui * k7 * vb.w;
      size_t o = 1 + (size_t)i * M_V + jb;
      out[o]     = t0; out[o + 1] = t1; out[o + 2] = t2; out[o + 3] = t3;
      out[o + 4] = t4; out[o + 5] = t5; out[o + 6] = t6; out[o + 7] = t7;
      contrib += t0 * (-__logf(k0)) + t1 * (-__logf(k1)) + t2 * (-__logf(k2)) + t3 * (-__logf(k3))
               + t4 * (-__logf(k4)) + t5 * (-__logf(k5)) + t6 * (-__logf(k6)) + t7 * (-__logf(k7));
      sp0 += k0 * ui; sp1 += k1 * ui; sp2 += k2 * ui; sp3 += k3 * ui;
      sp4 += k4 * ui; sp5 += k5 * ui; sp6 += k6 * ui; sp7 += k7 * ui;
    }
    float* sb = sPart + (size_t)by * M_V + jb;
    *(float4*)sb       = make_float4(sp0, sp1, sp2, sp3);
    *(float4*)(sb + 4) = make_float4(sp4, sp5, sp6, sp7);
  }
  contrib = blockReduce256(contrib) * INV_ALPHA;
  if (threadIdx.x == 0) lossPart[by * F8BLK + blockIdx.x] = contrib;
}

__global__ __launch_bounds__(256) void errfinish_kernel(const float* __restrict__ sPart,
                                                        const float* __restrict__ v_,
                                                        float* errAcc) {
  int j = blockIdx.x * 256 + threadIdx.x;
  float e = 0.0f;
  if (j < M_V) {
    float s = 0.0f;
    #pragma unroll
    for (int q = 0; q < 64; ++q) s += sPart[(size_t)q * M_V + j];
    e = fabsf(v_[j] * s - B_VAL);
  }
  e = blockReduce256(e);
  if (threadIdx.x == 0) atomicAdd(errAcc, e);
}

__global__ void setflag_kernel(const float* errAcc, int* notconv) {
  *notconv = (errAcc[0] > THR) ? 1 : 0;
}
__global__ void set1_kernel(int* p) { *p = 1; }

__global__ __launch_bounds__(256) void finishloss_kernel(const float* __restrict__ lossPart,
                                                         float* out, int np_) {
  float s = 0.0f;
  for (int i = threadIdx.x; i < np_; i += 256) s += lossPart[i];
  s = blockReduce256(s);
  if (threadIdx.x == 0) out[0] = s;
}

// ---- gated safety net: full reference Sinkhorn (grid-size-agnostic) ----
template <typename KT>
__global__ __launch_bounds__(256, 4) void sinkhorn_coop(const KT* Km,
                                                        float* __restrict__ u,
                                                        float* __restrict__ v,
                                                        float* __restrict__ s,
                                                        float* __restrict__ errAcc,
                                                        const int* __restrict__ notconv) {
  if (*notconv == 0) return;   // uniform across grid
  cg::grid_group grid = cg::this_grid();
  __shared__ float su[N_T];
  __shared__ float red[8][64];
  const int tid = threadIdx.x;
  const int bid = blockIdx.x;
  const int nb  = gridDim.x;
  {
    int g0 = bid * 256 + tid;
    if (g0 < N_T) u[g0] = A_VAL;
    if (g0 < 2) errAcc[g0] = 0.0f;
  }
  grid.sync();
  for (int t = 1; t <= 100; ++t) {
    const bool check = (t == 2) || (t == 52);
    for (int i = tid; i < N_T; i += 256) su[i] = u[i];
    __syncthreads();
    const int g = tid >> 5, jl = tid & 31;
    float eacc = 0.0f;
    for (int c = bid; c < NCHUNK; c += nb) {
      const int j0 = c * 64;
      const int jj = j0 + jl * 2;
      float p0 = 0.f, p1 = 0.f;
      if (jj < M_V) {
        const KT* base = Km + (size_t)(g * 128) * M_V + jj;
        #pragma unroll 4
        for (int i = 0; i < 128; ++i) {
          float k0 = (float)base[(size_t)i * M_V];
          float k1 = (float)base[(size_t)i * M_V + 1];
          float uu = su[g * 128 + i];
          p0 += k0 * uu; p1 += k1 * uu;
        }
      }
      red[g][jl * 2]     = p0;
      red[g][jl * 2 + 1] = p1;
      __syncthreads();
      if (tid < 64) {
        int j = j0 + tid;
        if (j < M_V) {
          float st = 0.f;
          #pragma unroll
          for (int q = 0; q < 8; ++q) st += red[q][tid];
          if (check) {
            s[j] = st;
            eacc += fabsf(v[j] * st - B_VAL);
          } else {
            v[j] = B_VAL / (st + EPSV);
          }
        }
      }
      __syncthreads();
    }
    if (check) {
      float e = blockReduce256(eacc);
      if (tid == 0) atomicAdd(&errAcc[t == 2 ? 0 : 1], e);
    }
    grid.sync();
    if (check) {
      float e = errAcc[t == 2 ? 0 : 1];
      if (e <= THR) break;
      if (tid < 64) {
        for (int c = bid; c < NCHUNK; c += nb) {
          int j = c * 64 + tid;
          if (j < M_V) v[j] = B_VAL / (s[j] + EPSV);
        }
      }
      grid.sync();
    }
    for (int i = bid; i < N_T; i += nb) {
      float p = 0.f;
      const KT* row = Km + (size_t)i * M_V;
      for (int j = tid; j < M_V; j += 256) p += (float)row[j] * v[j];
      p = blockReduce256(p);
      if (tid == 0) u[i] = A_VAL / (p + EPSV);
    }
    grid.sync();
  }
}

// ---- gated redo final ----
template <typename KT>
__global__ __launch_bounds__(256) void final_kernel(const KT* Kmat,
                                                    const float* __restrict__ u,
                                                    const float* __restrict__ v,
                                                    float* out,
                                                    float* __restrict__ partials,
                                                    const int* __restrict__ gate) {
  if (*gate == 0) return;
  int j = blockIdx.x * 256 + threadIdx.x;
  float contrib = 0.0f;
  if (j < M_V) {
    float vj = v[j];
    #pragma unroll 4
    for (int r = 0; r < 16; ++r) {
      int i = blockIdx.y * 16 + r;
      size_t idx = (size_t)i * M_V + j;
      float k = (float)Kmat[idx];
      float tr = u[i] * k * vj;
      float m = -__logf(k) * INV_ALPHA;
      out[1 + idx] = tr;
      contrib += tr * m;
    }
  }
  contrib = blockReduce256(contrib);
  if (threadIdx.x == 0) partials[blockIdx.y * gridDim.x + blockIdx.x] = contrib;
}

__global__ __launch_bounds__(256) void finish_kernel(const float* __restrict__ partials,
                                                     float* out, int np_,
                                                     const int* __restrict__ gate) {
  if (*gate == 0) return;
  float s = 0.0f;
  for (int i = threadIdx.x; i < np_; i += 256) s += partials[i];
  s = blockReduce256(s);
  if (threadIdx.x == 0) out[0] = s;
}

// ======== fallback path (ws too small): exact f32 ========
__global__ __launch_bounds__(256) void sumsq_kernel(const float* __restrict__ in,
                                                    float* __restrict__ o, int rows) {
  int r = blockIdx.x;
  if (r >= rows) return;
  float v = in[(size_t)r * DIMS + threadIdx.x];
  float s = blockReduce256(v * v);
  if (threadIdx.x == 0) o[r] = s;
}

#define BM 64
#define BN 64
#define BK 32
__global__ __launch_bounds__(256) void gemm_k_kernel(const float* __restrict__ x,
                                                     const float* __restrict__ y,
                                                     const float* __restrict__ xx,
                                                     const float* __restrict__ yy,
                                                     float* Kmat) {
  __shared__ float As[BK][BM];
  __shared__ float Bs[BK][BN + 1];
  int tid = threadIdx.x;
  int i0 = blockIdx.y * BM;
  int j0 = blockIdx.x * BN;
  int tx = tid & 15, ty = tid >> 4;
  float acc[4][4] = {};
  for (int k0 = 0; k0 < DIMS; k0 += BK) {
    #pragma unroll
    for (int l = tid; l < 512; l += 256) {
      int r = l >> 3, kq = l & 7;
      float4 a4 = *(const float4*)&x[(size_t)(i0 + r) * DIMS + k0 + kq * 4];
      As[kq * 4 + 0][r] = a4.x; As[kq * 4 + 1][r] = a4.y;
      As[kq * 4 + 2][r] = a4.z; As[kq * 4 + 3][r] = a4.w;
    }
    #pragma unroll
    for (int l = tid; l < 512; l += 256) {
      int r = l >> 3, kq = l & 7;
      int j = j0 + r;
      float4 b4 = make_float4(0.f, 0.f, 0.f, 0.f);
      if (j < M_V) b4 = *(const float4*)&y[(size_t)j * DIMS + k0 + kq * 4];
      Bs[kq * 4 + 0][r] = b4.x; Bs[kq * 4 + 1][r] = b4.y;
      Bs[kq * 4 + 2][r] = b4.z; Bs[kq * 4 + 3][r] = b4.w;
    }
    __syncthreads();
    #pragma unroll
    for (int k = 0; k < BK; ++k) {
      float a[4], b[4];
      #pragma unroll
      for (int r = 0; r < 4; ++r) a[r] = As[k][ty * 4 + r];
      #pragma unroll
      for (int c = 0; c < 4; ++c) b[c] = Bs[k][tx * 4 + c];
      #pragma unroll
      for (int r = 0; r < 4; ++r)
        #pragma unroll
        for (int c = 0; c < 4; ++c) acc[r][c] += a[r] * b[c];
    }
    __syncthreads();
  }
  #pragma unroll
  for (int r = 0; r < 4; ++r) {
    int i = i0 + ty * 4 + r;
    float xxi = xx[i];
    #pragma unroll
    for (int c = 0; c < 4; ++c) {
      int j = j0 + tx * 4 + c;
      if (j < M_V) {
        float m = xxi + yy[j] - 2.0f * acc[r][c];
        Kmat[(size_t)i * M_V + j] = __expf(-ALPHA * m);
      }
    }
  }
}

extern "C" void kernel_launch(void* const* d_in, const int* in_sizes, int n_in,
                              void* d_out, int out_size, void* d_ws, size_t ws_size,
                              hipStream_t stream) {
  const float* x = (const float*)d_in[0];
  const float* y = (const float*)d_in[1];
  float* out = (float*)d_out;

  uintptr_t wp = (uintptr_t)d_ws;
  uintptr_t wend = (uintptr_t)d_ws + ws_size;
  auto alloc = [&](size_t bytes) -> void* {
    wp = (wp + 255) & ~(uintptr_t)255;
    void* p = (void*)wp;
    wp += bytes;
    return p;
  };
  float* u        = (float*)alloc((size_t)N_T * 4);
  float* v        = (float*)alloc((size_t)M_V * 4);
  float* s        = (float*)alloc((size_t)M_V * 4);
  float* xx       = (float*)alloc((size_t)N_T * 4);
  float* yy       = (float*)alloc((size_t)M_V * 4);
  float* partials = (float*)alloc((size_t)NPART * 4);
  float* lossPart = (float*)alloc((size_t)1600 * 4);
  float* rowPart  = (float*)alloc((size_t)2 * N_T * 4);
  float* errAcc   = (float*)alloc(64);
  int*   notconv  = (int*)alloc(64);
  float* colsumPart = (float*)alloc((size_t)16 * NPAD * 4);
  float* sPart    = (float*)alloc((size_t)64 * M_V * 4);   // 12.8 MB

  const size_t apbytes = (size_t)N_T * 512 * 2;    // 1 MB
  const size_t bpbytes = (size_t)NPAD * 256 * 2;   // 25.6 MB
  const size_t khbytes = (size_t)N_T * M_V * 2;    // 100 MB
  const size_t kfbytes = (size_t)N_T * M_V * 4;    // 200 MB (fallback)

  bool fast = ((wp + 1024) + apbytes + bpbytes + khbytes) <= wend;

  // device capacity queries (pure host queries; graph-capture safe)
  int dev = 0;
  hipGetDevice(&dev);
  int numCU = 256;
  hipDeviceGetAttribute(&numCU, hipDeviceAttributeMultiprocessorCount, dev);

  if (fast) {
    unsigned short* Ap = (unsigned short*)alloc(apbytes);
    unsigned short* Bp = (unsigned short*)alloc(bpbytes);
    _Float16*       Kh = (_Float16*)alloc(khbytes);

    pack_kernel<<<N_T / 2 + NPAD / 2, 256, 0, stream>>>(x, y, Ap, Bp, xx, yy);
    mfma_gemm_kernel<<<49 * 64, 256, 0, stream>>>(Ap, Bp, xx, yy, Kh, colsumPart);

    int occMega = 0;
    hipOccupancyMaxActiveBlocksPerMultiprocessor(&occMega, mega_lite, 256, 0);
    long megaCap = (long)occMega * numCU;
    int megaGrid = (int)(megaCap < 512 ? megaCap : 512);

    bool megaDone = false;
    if (megaGrid >= 128) {
      void* args[] = {(void*)&Kh, (void*)&colsumPart, (void*)&u, (void*)&v,
                      (void*)&errAcc, (void*)&lossPart, (void*)&sPart,
                      (void*)&out, (void*)&notconv};
      hipError_t lerr = hipLaunchCooperativeKernel(reinterpret_cast<void*>(mega_lite),
                                                   dim3(megaGrid), dim3(256), args, 0, stream);
      megaDone = (lerr == hipSuccess);
    }
    if (!megaDone) {
      // round-6 proven split sequence
      v1_kernel<<<CBLK, 256, 0, stream>>>(colsumPart, v, errAcc);
      rowpass_kernel<<<dim3(2, N_T), 256, 0, stream>>>(Kh, v, rowPart);
      u_kernel<<<N_T / 256, 256, 0, stream>>>(rowPart, u);
      specfinal_kernel<<<dim3(F8BLK, 64), 256, 0, stream>>>(Kh, u, v, out, sPart, lossPart);
      errfinish_kernel<<<CBLK, 256, 0, stream>>>(sPart, v, errAcc);
      setflag_kernel<<<1, 1, 0, stream>>>(errAcc, notconv);
      finishloss_kernel<<<1, 256, 0, stream>>>(lossPart, out, LPART);
    }

    // gated safety net (no-op when converged at first check)
    int occS = 0;
    hipOccupancyMaxActiveBlocksPerMultiprocessor(&occS, sinkhorn_coop<_Float16>, 256, 0);
    long sCap = (long)occS * numCU;
    int sGrid = (int)(sCap < 1024 ? sCap : 1024);
    if (sGrid < 1) sGrid = 1;
    void* coopArgs[] = {(void*)&Kh, (void*)&u, (void*)&v, (void*)&s,
                        (void*)&errAcc, (void*)&notconv};
    hipLaunchCooperativeKernel(reinterpret_cast<void*>(sinkhorn_coop<_Float16>),
                               dim3(sGrid), dim3(256), coopArgs, 0, stream);
    final_kernel<_Float16><<<dim3(CBLK, 64), 256, 0, stream>>>(Kh, u, v, out, partials, notconv);
    finish_kernel<<<1, 256, 0, stream>>>(partials, out, NPART, notconv);
  } else {
    sumsq_kernel<<<N_T, 256, 0, stream>>>(x, xx, N_T);
    sumsq_kernel<<<M_V, 256, 0, stream>>>(y, yy, M_V);
    bool k_in_ws = ((wp + 512) + kfbytes) <= wend;
    float* Kmat = k_in_ws ? (float*)alloc(kfbytes) : out + 1;
    gemm_k_kernel<<<dim3((M_V + BN - 1) / BN, N_T / BM), 256, 0, stream>>>(x, y, xx, yy, Kmat);
    set1_kernel<<<1, 1, 0, stream>>>(notconv);
    int occS = 0;
    hipOccupancyMaxActiveBlocksPerMultiprocessor(&occS, sinkhorn_coop<float>, 256, 0);
    long sCap = (long)occS * numCU;
    int sGrid = (int)(sCap < 1024 ? sCap : 1024);
    if (sGrid < 1) sGrid = 1;
    void* coopArgs[] = {(void*)&Kmat, (void*)&u, (void*)&v, (void*)&s,
                        (void*)&errAcc, (void*)&notconv};
    hipLaunchCooperativeKernel(reinterpret_cast<void*>(sinkhorn_coop<float>),
                               dim3(sGrid), dim3(256), coopArgs, 0, stream);
    final_kernel<float><<<dim3(CBLK, 64), 256, 0, stream>>>(Kmat, u, v, out, partials, notconv);
    finish_kernel<<<1, 256, 0, stream>>>(partials, out, NPART, notconv);
  }
}

// Round 10
// 261.132 us; speedup vs baseline: 1.4615x; 1.4615x over previous
//
#include <hip/hip_runtime.h>
#include <hip/hip_cooperative_groups.h>
#include <cstdint>

namespace cg = cooperative_groups;

#define N_T 1024
#define M_V 50000
#define DIMS 256
#define NPAD 50048
#define GPANELS 391         // 50048 / 128
#define CBLK 196            // ceil(50000/256)
#define NPART (CBLK * 64)
#define NCHUNK 782          // coop colpass chunks (gated path)
#define J8TOT 6250          // 50000/8 columns-of-8
#define F8BLK 25            // ceil(6250/256)
#define LPART (F8BLK * 64)

constexpr float ALPHA     = 0.05f;
constexpr float INV_ALPHA = 20.0f;
constexpr float A_VAL     = 1.0f / 1024.0f;
constexpr float B_VAL     = 1.0f / 50000.0f;
constexpr float THR       = 0.005f;
constexpr float EPSV      = 1e-16f;

typedef short    bf16x8 __attribute__((ext_vector_type(8)));
typedef float    f32x4  __attribute__((ext_vector_type(4)));
typedef _Float16 half8v __attribute__((ext_vector_type(8)));

__device__ __forceinline__ float blockReduce256(float val) {
  #pragma unroll
  for (int off = 32; off; off >>= 1) val += __shfl_down(val, off, 64);
  __shared__ float redw[4];
  int lane = threadIdx.x & 63;
  int wid  = threadIdx.x >> 6;
  if (lane == 0) redw[wid] = val;
  __syncthreads();
  float r = 0.0f;
  if (threadIdx.x == 0) r = redw[0] + redw[1] + redw[2] + redw[3];
  __syncthreads();
  return r;
}

__device__ __forceinline__ unsigned short f2bf(float f) {
  union { float f; unsigned u; } c{f};
  unsigned r = c.u + 0x7FFF + ((c.u >> 16) & 1);   // RNE
  return (unsigned short)(r >> 16);
}
__device__ __forceinline__ float bf2f(unsigned short b) {
  union { unsigned u; float f; } c{(unsigned)b << 16};
  return c.f;
}

__device__ __forceinline__ void gload16(const void* g, void* l) {
  __builtin_amdgcn_global_load_lds((const __attribute__((address_space(1))) unsigned int*)g,
                                   (__attribute__((address_space(3))) unsigned int*)l, 16, 0, 0);
}

// ---- fused pack: blocks [0,512) pack x -> A'=[xh|xl]+xx; rest pack y -> B'=[yh]+yy ----
__global__ __launch_bounds__(256) void pack_kernel(const float* __restrict__ x,
                                                   const float* __restrict__ y,
                                                   unsigned short* __restrict__ Ap,
                                                   unsigned short* __restrict__ Bp,
                                                   float* __restrict__ xx,
                                                   float* __restrict__ yy) {
  __shared__ float rr[4];
  int lane = threadIdx.x & 63, wid = threadIdx.x >> 6;
  if (blockIdx.x < N_T / 2) {
    int r = blockIdx.x * 2 + (threadIdx.x >> 7);
    int k = (threadIdx.x & 127) * 2;
    float2 vx = *(const float2*)&x[(size_t)r * DIMS + k];
    ushort2 h2, l2;
    h2.x = f2bf(vx.x); h2.y = f2bf(vx.y);
    l2.x = f2bf(vx.x - bf2f(h2.x)); l2.y = f2bf(vx.y - bf2f(h2.y));
    *(ushort2*)&Ap[(size_t)r * 512 + k]       = h2;
    *(ushort2*)&Ap[(size_t)r * 512 + 256 + k] = l2;
    float ssq = vx.x * vx.x + vx.y * vx.y;
    #pragma unroll
    for (int off = 32; off; off >>= 1) ssq += __shfl_down(ssq, off, 64);
    if (lane == 0) rr[wid] = ssq;
    __syncthreads();
    if ((threadIdx.x & 127) == 0) xx[r] = rr[wid] + rr[wid + 1];
  } else {
    int r = (blockIdx.x - N_T / 2) * 2 + (threadIdx.x >> 7);
    int k = (threadIdx.x & 127) * 2;
    ushort2 h2 = {0, 0};
    float ssq = 0.0f;
    if (r < M_V) {
      float2 vy = *(const float2*)&y[(size_t)r * DIMS + k];
      h2.x = f2bf(vy.x); h2.y = f2bf(vy.y);
      ssq = vy.x * vy.x + vy.y * vy.y;
    }
    *(ushort2*)&Bp[(size_t)r * 256 + k] = h2;
    #pragma unroll
    for (int off = 32; off; off >>= 1) ssq += __shfl_down(ssq, off, 64);
    if (lane == 0) rr[wid] = ssq;
    __syncthreads();
    if ((threadIdx.x & 127) == 0 && r < M_V) yy[r] = rr[wid] + rr[wid + 1];
  }
}

// ---- MFMA GEMM -> f16 K + fused column-sum partials (2-phase dbuf, vmcnt(6)) ----
__global__ __launch_bounds__(256) void mfma_gemm_kernel(const unsigned short* __restrict__ Ap,
                                                        const unsigned short* __restrict__ Bp,
                                                        const float* __restrict__ xx,
                                                        const float* __restrict__ yy,
                                                        _Float16* __restrict__ Kh,
                                                        float* __restrict__ colsumPart) {
  const int t  = blockIdx.x & 63;
  const int gb = blockIdx.x >> 6;
  const int panel = gb * 8 + (t & 7);
  const int rt    = t >> 3;
  if (panel >= GPANELS) return;
  const int i0 = rt * 128;
  const int j0 = panel * 128;

  __shared__ unsigned short Ah[2][128][32];
  __shared__ unsigned short Al[2][128][32];
  __shared__ unsigned short Bs[2][128][32];
  const int tid  = threadIdx.x;
  const int lane = tid & 63;
  const int wid  = tid >> 6;
  const int wr = wid >> 1, wc = wid & 1;

  f32x4 acc[4][4];
  #pragma unroll
  for (int m = 0; m < 4; ++m)
    #pragma unroll
    for (int n = 0; n < 4; ++n) acc[m][n] = (f32x4){0.f, 0.f, 0.f, 0.f};

  const int srow  = lane >> 2;
  const int sslot = lane & 3;

  auto STAGE = [&](int b, int k0) {
    #pragma unroll
    for (int q = 0; q < 2; ++q) {
      int rbase = (wid * 2 + q) * 16;
      int row = rbase + srow;
      int cg_ = sslot ^ ((row >> 1) & 3);
      gload16(Ap + (size_t)(i0 + row) * 512 + k0 + cg_ * 8,       &Ah[b][rbase][0]);
      gload16(Ap + (size_t)(i0 + row) * 512 + 256 + k0 + cg_ * 8, &Al[b][rbase][0]);
      gload16(Bp + (size_t)(j0 + row) * 256 + k0 + cg_ * 8,       &Bs[b][rbase][0]);
    }
  };

  STAGE(0, 0);
  int cur = 0;
  #pragma unroll
  for (int step = 0; step < 8; ++step) {
    if (step < 7) {
      STAGE(cur ^ 1, (step + 1) * 32);
      asm volatile("s_waitcnt vmcnt(6)" ::: "memory");
    } else {
      asm volatile("s_waitcnt vmcnt(0)" ::: "memory");
    }
    __builtin_amdgcn_s_barrier();
    __builtin_amdgcn_sched_barrier(0);
    bf16x8 ah[4], al[4], bb[4];
    #pragma unroll
    for (int m = 0; m < 4; ++m) {
      int row = wr * 64 + m * 16 + (lane & 15);
      int sl  = (lane >> 4) ^ ((row >> 1) & 3);
      ah[m] = *(const bf16x8*)&Ah[cur][row][sl * 8];
      al[m] = *(const bf16x8*)&Al[cur][row][sl * 8];
    }
    #pragma unroll
    for (int n = 0; n < 4; ++n) {
      int col = wc * 64 + n * 16 + (lane & 15);
      int sl  = (lane >> 4) ^ ((col >> 1) & 3);
      bb[n] = *(const bf16x8*)&Bs[cur][col][sl * 8];
    }
    #pragma unroll
    for (int m = 0; m < 4; ++m)
      #pragma unroll
      for (int n = 0; n < 4; ++n) {
        acc[m][n] = __builtin_amdgcn_mfma_f32_16x16x32_bf16(ah[m], bb[n], acc[m][n], 0, 0, 0);
        acc[m][n] = __builtin_amdgcn_mfma_f32_16x16x32_bf16(al[m], bb[n], acc[m][n], 0, 0, 0);
      }
    asm volatile("s_waitcnt lgkmcnt(0)" ::: "memory");
    __builtin_amdgcn_sched_barrier(0);
    __builtin_amdgcn_s_barrier();
    cur ^= 1;
  }

  float csum[4] = {0.f, 0.f, 0.f, 0.f};
  #pragma unroll
  for (int m = 0; m < 4; ++m) {
    int rowb = i0 + wr * 64 + m * 16 + (lane >> 4) * 4;
    #pragma unroll
    for (int n = 0; n < 4; ++n) {
      int col = j0 + wc * 64 + n * 16 + (lane & 15);
      float yyc = (col < M_V) ? yy[col] : 0.0f;
      #pragma unroll
      for (int r = 0; r < 4; ++r) {
        float mval = xx[rowb + r] + yyc - 2.0f * acc[m][n][r];
        _Float16 kh = (_Float16)__expf(-ALPHA * mval);
        if (col < M_V) Kh[(size_t)(rowb + r) * M_V + col] = kh;
        csum[n] += (float)kh;
      }
    }
  }
  #pragma unroll
  for (int n = 0; n < 4; ++n) {
    float c = csum[n];
    c += __shfl_xor(c, 16, 64);
    c += __shfl_xor(c, 32, 64);
    if (lane < 16) {
      int col = j0 + wc * 64 + n * 16 + lane;
      colsumPart[(size_t)(rt * 2 + wr) * NPAD + col] = c;
    }
  }
}

// ---- v1: v_j = b / (colsum_j * a + eps); reset errAcc + ticket counter ----
__global__ __launch_bounds__(256) void v1_kernel(const float* __restrict__ cp,
                                                 float* __restrict__ v,
                                                 float* __restrict__ errAcc,
                                                 int* __restrict__ counter) {
  int j = blockIdx.x * 256 + threadIdx.x;
  if (j == 0) { errAcc[0] = 0.0f; *counter = 0; }
  if (j < M_V) {
    float s = 0.0f;
    #pragma unroll
    for (int q = 0; q < 16; ++q) s += cp[(size_t)q * NPAD + j];
    v[j] = B_VAL / (s * A_VAL + EPSV);
  }
}

// ---- rowpass on f16 K: grid (2, N_T) ----
__global__ __launch_bounds__(256) void rowpass_kernel(const _Float16* __restrict__ Kh,
                                                      const float* __restrict__ v,
                                                      float* __restrict__ rowPart) {
  const int i = blockIdx.y;
  const int c = blockIdx.x;  // 0 or 1
  const half8v* K8 = (const half8v*)(Kh + (size_t)i * M_V);
  const float4* v4 = (const float4*)v;
  float p = 0.0f;
  int q = c * 3125 + threadIdx.x;
  #pragma unroll
  for (int it = 0; it < 12; ++it, q += 256) {
    half8v k8 = K8[q];
    float4 va = v4[q * 2], vb = v4[q * 2 + 1];
    p += (float)k8[0] * va.x + (float)k8[1] * va.y + (float)k8[2] * va.z + (float)k8[3] * va.w
       + (float)k8[4] * vb.x + (float)k8[5] * vb.y + (float)k8[6] * vb.z + (float)k8[7] * vb.w;
  }
  if (threadIdx.x < 53) {
    int q2 = c * 3125 + 3072 + threadIdx.x;
    half8v k8 = K8[q2];
    float4 va = v4[q2 * 2], vb = v4[q2 * 2 + 1];
    p += (float)k8[0] * va.x + (float)k8[1] * va.y + (float)k8[2] * va.z + (float)k8[3] * va.w
       + (float)k8[4] * vb.x + (float)k8[5] * vb.y + (float)k8[6] * vb.z + (float)k8[7] * vb.w;
  }
  p = blockReduce256(p);
  if (threadIdx.x == 0) rowPart[c * N_T + i] = p;
}

__global__ void u_kernel(const float* __restrict__ rowPart, float* __restrict__ u) {
  int i = blockIdx.x * 256 + threadIdx.x;
  u[i] = A_VAL / (rowPart[i] + rowPart[N_T + i] + EPSV);
}

// ---- speculative final: 8 cols/thread; transp + loss partials + s partials ----
__global__ __launch_bounds__(256) void specfinal_kernel(const _Float16* __restrict__ Kh,
                                                        const float* __restrict__ u_,
                                                        const float* __restrict__ v_,
                                                        float* __restrict__ out,
                                                        float* __restrict__ sPart,
                                                        float* __restrict__ lossPart) {
  const int j8 = blockIdx.x * 256 + threadIdx.x;
  const int by = blockIdx.y;
  float contrib = 0.0f;
  if (j8 < J8TOT) {
    const size_t jb = (size_t)j8 * 8;
    float4 va = ((const float4*)v_)[j8 * 2];
    float4 vb = ((const float4*)v_)[j8 * 2 + 1];
    float sp0 = 0.f, sp1 = 0.f, sp2 = 0.f, sp3 = 0.f;
    float sp4 = 0.f, sp5 = 0.f, sp6 = 0.f, sp7 = 0.f;
    #pragma unroll
    for (int r = 0; r < 16; ++r) {
      int i = by * 16 + r;
      half8v k8 = *(const half8v*)(Kh + (size_t)i * M_V + jb);
      float ui = u_[i];
      float k0 = (float)k8[0], k1 = (float)k8[1], k2 = (float)k8[2], k3 = (float)k8[3];
      float k4 = (float)k8[4], k5 = (float)k8[5], k6 = (float)k8[6], k7 = (float)k8[7];
      float t0 = ui * k0 * va.x, t1 = ui * k1 * va.y, t2 = ui * k2 * va.z, t3 = ui * k3 * va.w;
      float t4 = ui * k4 * vb.x, t5 = ui * k5 * vb.y, t6 = ui * k6 * vb.z, t7 = ui * k7 * vb.w;
      size_t o = 1 + (size_t)i * M_V + jb;
      out[o]     = t0; out[o + 1] = t1; out[o + 2] = t2; out[o + 3] = t3;
      out[o + 4] = t4; out[o + 5] = t5; out[o + 6] = t6; out[o + 7] = t7;
      contrib += t0 * (-__logf(k0)) + t1 * (-__logf(k1)) + t2 * (-__logf(k2)) + t3 * (-__logf(k3))
               + t4 * (-__logf(k4)) + t5 * (-__logf(k5)) + t6 * (-__logf(k6)) + t7 * (-__logf(k7));
      sp0 += k0 * ui; sp1 += k1 * ui; sp2 += k2 * ui; sp3 += k3 * ui;
      sp4 += k4 * ui; sp5 += k5 * ui; sp6 += k6 * ui; sp7 += k7 * ui;
    }
    float* sb = sPart + (size_t)by * M_V + jb;
    *(float4*)sb       = make_float4(sp0, sp1, sp2, sp3);
    *(float4*)(sb + 4) = make_float4(sp4, sp5, sp6, sp7);
  }
  contrib = blockReduce256(contrib) * INV_ALPHA;
  if (threadIdx.x == 0) lossPart[by * F8BLK + blockIdx.x] = contrib;
}

// ---- fused tail: err reduce + last-block loss total + notconv flag ----
__global__ __launch_bounds__(256) void tail_kernel(const float* __restrict__ sPart,
                                                   const float* __restrict__ v_,
                                                   const float* __restrict__ lossPart,
                                                   float* errAcc, int* counter,
                                                   float* out, int* notconv) {
  int j = blockIdx.x * 256 + threadIdx.x;
  float e = 0.0f;
  if (j < M_V) {
    float ss = 0.0f;
    #pragma unroll
    for (int q = 0; q < 64; ++q) ss += sPart[(size_t)q * M_V + j];
    e = fabsf(v_[j] * ss - B_VAL);
  }
  e = blockReduce256(e);
  __shared__ int lastFlag;
  if (threadIdx.x == 0) {
    atomicAdd(errAcc, e);
    __threadfence();
    int old = atomicAdd(counter, 1);
    lastFlag = (old == (int)gridDim.x - 1) ? 1 : 0;
  }
  __syncthreads();
  if (lastFlag) {
    float ls = 0.0f;
    for (int i = threadIdx.x; i < LPART; i += 256) ls += lossPart[i];
    ls = blockReduce256(ls);
    if (threadIdx.x == 0) {
      out[0] = ls;
      *notconv = (errAcc[0] > THR) ? 1 : 0;
    }
  }
}

__global__ void set1_kernel(int* p) { *p = 1; }

// ---- gated safety net: full reference Sinkhorn (grid-size-agnostic) ----
template <typename KT>
__global__ __launch_bounds__(256, 4) void sinkhorn_coop(const KT* Km,
                                                        float* __restrict__ u,
                                                        float* __restrict__ v,
                                                        float* __restrict__ s,
                                                        float* __restrict__ errAcc,
                                                        const int* __restrict__ notconv) {
  if (*notconv == 0) return;   // uniform across grid
  cg::grid_group grid = cg::this_grid();
  __shared__ float su[N_T];
  __shared__ float red[8][64];
  const int tid = threadIdx.x;
  const int bid = blockIdx.x;
  const int nb  = gridDim.x;
  {
    int g0 = bid * 256 + tid;
    if (g0 < N_T) u[g0] = A_VAL;
    if (g0 < 2) errAcc[g0] = 0.0f;
  }
  grid.sync();
  for (int t = 1; t <= 100; ++t) {
    const bool check = (t == 2) || (t == 52);
    for (int i = tid; i < N_T; i += 256) su[i] = u[i];
    __syncthreads();
    const int g = tid >> 5, jl = tid & 31;
    float eacc = 0.0f;
    for (int c = bid; c < NCHUNK; c += nb) {
      const int j0 = c * 64;
      const int jj = j0 + jl * 2;
      float p0 = 0.f, p1 = 0.f;
      if (jj < M_V) {
        const KT* base = Km + (size_t)(g * 128) * M_V + jj;
        #pragma unroll 4
        for (int i = 0; i < 128; ++i) {
          float k0 = (float)base[(size_t)i * M_V];
          float k1 = (float)base[(size_t)i * M_V + 1];
          float uu = su[g * 128 + i];
          p0 += k0 * uu; p1 += k1 * uu;
        }
      }
      red[g][jl * 2]     = p0;
      red[g][jl * 2 + 1] = p1;
      __syncthreads();
      if (tid < 64) {
        int j = j0 + tid;
        if (j < M_V) {
          float st = 0.f;
          #pragma unroll
          for (int q = 0; q < 8; ++q) st += red[q][tid];
          if (check) {
            s[j] = st;
            eacc += fabsf(v[j] * st - B_VAL);
          } else {
            v[j] = B_VAL / (st + EPSV);
          }
        }
      }
      __syncthreads();
    }
    if (check) {
      float e = blockReduce256(eacc);
      if (tid == 0) atomicAdd(&errAcc[t == 2 ? 0 : 1], e);
    }
    grid.sync();
    if (check) {
      float e = errAcc[t == 2 ? 0 : 1];
      if (e <= THR) break;
      if (tid < 64) {
        for (int c = bid; c < NCHUNK; c += nb) {
          int j = c * 64 + tid;
          if (j < M_V) v[j] = B_VAL / (s[j] + EPSV);
        }
      }
      grid.sync();
    }
    for (int i = bid; i < N_T; i += nb) {
      float p = 0.f;
      const KT* row = Km + (size_t)i * M_V;
      for (int j = tid; j < M_V; j += 256) p += (float)row[j] * v[j];
      p = blockReduce256(p);
      if (tid == 0) u[i] = A_VAL / (p + EPSV);
    }
    grid.sync();
  }
}

// ---- gated redo final ----
template <typename KT>
__global__ __launch_bounds__(256) void final_kernel(const KT* Kmat,
                                                    const float* __restrict__ u,
                                                    const float* __restrict__ v,
                                                    float* out,
                                                    float* __restrict__ partials,
                                                    const int* __restrict__ gate) {
  if (*gate == 0) return;
  int j = blockIdx.x * 256 + threadIdx.x;
  float contrib = 0.0f;
  if (j < M_V) {
    float vj = v[j];
    #pragma unroll 4
    for (int r = 0; r < 16; ++r) {
      int i = blockIdx.y * 16 + r;
      size_t idx = (size_t)i * M_V + j;
      float k = (float)Kmat[idx];
      float tr = u[i] * k * vj;
      float m = -__logf(k) * INV_ALPHA;
      out[1 + idx] = tr;
      contrib += tr * m;
    }
  }
  contrib = blockReduce256(contrib);
  if (threadIdx.x == 0) partials[blockIdx.y * gridDim.x + blockIdx.x] = contrib;
}

__global__ __launch_bounds__(256) void finish_kernel(const float* __restrict__ partials,
                                                     float* out, int np_,
                                                     const int* __restrict__ gate) {
  if (*gate == 0) return;
  float s = 0.0f;
  for (int i = threadIdx.x; i < np_; i += 256) s += partials[i];
  s = blockReduce256(s);
  if (threadIdx.x == 0) out[0] = s;
}

// ======== fallback path (ws too small): exact f32 ========
__global__ __launch_bounds__(256) void sumsq_kernel(const float* __restrict__ in,
                                                    float* __restrict__ o, int rows) {
  int r = blockIdx.x;
  if (r >= rows) return;
  float v = in[(size_t)r * DIMS + threadIdx.x];
  float s = blockReduce256(v * v);
  if (threadIdx.x == 0) o[r] = s;
}

#define BM 64
#define BN 64
#define BK 32
__global__ __launch_bounds__(256) void gemm_k_kernel(const float* __restrict__ x,
                                                     const float* __restrict__ y,
                                                     const float* __restrict__ xx,
                                                     const float* __restrict__ yy,
                                                     float* Kmat) {
  __shared__ float As[BK][BM];
  __shared__ float Bs[BK][BN + 1];
  int tid = threadIdx.x;
  int i0 = blockIdx.y * BM;
  int j0 = blockIdx.x * BN;
  int tx = tid & 15, ty = tid >> 4;
  float acc[4][4] = {};
  for (int k0 = 0; k0 < DIMS; k0 += BK) {
    #pragma unroll
    for (int l = tid; l < 512; l += 256) {
      int r = l >> 3, kq = l & 7;
      float4 a4 = *(const float4*)&x[(size_t)(i0 + r) * DIMS + k0 + kq * 4];
      As[kq * 4 + 0][r] = a4.x; As[kq * 4 + 1][r] = a4.y;
      As[kq * 4 + 2][r] = a4.z; As[kq * 4 + 3][r] = a4.w;
    }
    #pragma unroll
    for (int l = tid; l < 512; l += 256) {
      int r = l >> 3, kq = l & 7;
      int j = j0 + r;
      float4 b4 = make_float4(0.f, 0.f, 0.f, 0.f);
      if (j < M_V) b4 = *(const float4*)&y[(size_t)j * DIMS + k0 + kq * 4];
      Bs[kq * 4 + 0][r] = b4.x; Bs[kq * 4 + 1][r] = b4.y;
      Bs[kq * 4 + 2][r] = b4.z; Bs[kq * 4 + 3][r] = b4.w;
    }
    __syncthreads();
    #pragma unroll
    for (int k = 0; k < BK; ++k) {
      float a[4], b[4];
      #pragma unroll
      for (int r = 0; r < 4; ++r) a[r] = As[k][ty * 4 + r];
      #pragma unroll
      for (int c = 0; c < 4; ++c) b[c] = Bs[k][tx * 4 + c];
      #pragma unroll
      for (int r = 0; r < 4; ++r)
        #pragma unroll
        for (int c = 0; c < 4; ++c) acc[r][c] += a[r] * b[c];
    }
    __syncthreads();
  }
  #pragma unroll
  for (int r = 0; r < 4; ++r) {
    int i = i0 + ty * 4 + r;
    float xxi = xx[i];
    #pragma unroll
    for (int c = 0; c < 4; ++c) {
      int j = j0 + tx * 4 + c;
      if (j < M_V) {
        float m = xxi + yy[j] - 2.0f * acc[r][c];
        Kmat[(size_t)i * M_V + j] = __expf(-ALPHA * m);
      }
    }
  }
}

extern "C" void kernel_launch(void* const* d_in, const int* in_sizes, int n_in,
                              void* d_out, int out_size, void* d_ws, size_t ws_size,
                              hipStream_t stream) {
  const float* x = (const float*)d_in[0];
  const float* y = (const float*)d_in[1];
  float* out = (float*)d_out;

  uintptr_t wp = (uintptr_t)d_ws;
  uintptr_t wend = (uintptr_t)d_ws + ws_size;
  auto alloc = [&](size_t bytes) -> void* {
    wp = (wp + 255) & ~(uintptr_t)255;
    void* p = (void*)wp;
    wp += bytes;
    return p;
  };
  float* u        = (float*)alloc((size_t)N_T * 4);
  float* v        = (float*)alloc((size_t)M_V * 4);
  float* s        = (float*)alloc((size_t)M_V * 4);
  float* xx       = (float*)alloc((size_t)N_T * 4);
  float* yy       = (float*)alloc((size_t)M_V * 4);
  float* partials = (float*)alloc((size_t)NPART * 4);
  float* lossPart = (float*)alloc((size_t)LPART * 4);
  float* rowPart  = (float*)alloc((size_t)2 * N_T * 4);
  float* errAcc   = (float*)alloc(64);
  int*   notconv  = (int*)alloc(64);
  int*   counter  = (int*)alloc(64);
  float* colsumPart = (float*)alloc((size_t)16 * NPAD * 4);
  float* sPart    = (float*)alloc((size_t)64 * M_V * 4);   // 12.8 MB

  const size_t apbytes = (size_t)N_T * 512 * 2;    // 1 MB
  const size_t bpbytes = (size_t)NPAD * 256 * 2;   // 25.6 MB
  const size_t khbytes = (size_t)N_T * M_V * 2;    // 100 MB
  const size_t kfbytes = (size_t)N_T * M_V * 4;    // 200 MB (fallback)

  bool fast = ((wp + 1024) + apbytes + bpbytes + khbytes) <= wend;

  int dev = 0;
  hipGetDevice(&dev);
  int numCU = 256;
  hipDeviceGetAttribute(&numCU, hipDeviceAttributeMultiprocessorCount, dev);

  if (fast) {
    unsigned short* Ap = (unsigned short*)alloc(apbytes);
    unsigned short* Bp = (unsigned short*)alloc(bpbytes);
    _Float16*       Kh = (_Float16*)alloc(khbytes);

    pack_kernel<<<N_T / 2 + NPAD / 2, 256, 0, stream>>>(x, y, Ap, Bp, xx, yy);
    mfma_gemm_kernel<<<49 * 64, 256, 0, stream>>>(Ap, Bp, xx, yy, Kh, colsumPart);

    v1_kernel<<<CBLK, 256, 0, stream>>>(colsumPart, v, errAcc, counter);
    rowpass_kernel<<<dim3(2, N_T), 256, 0, stream>>>(Kh, v, rowPart);
    u_kernel<<<N_T / 256, 256, 0, stream>>>(rowPart, u);
    specfinal_kernel<<<dim3(F8BLK, 64), 256, 0, stream>>>(Kh, u, v, out, sPart, lossPart);
    tail_kernel<<<CBLK, 256, 0, stream>>>(sPart, v, lossPart, errAcc, counter, out, notconv);

    // gated safety net (no-op when converged at first check)
    int occS = 0;
    hipOccupancyMaxActiveBlocksPerMultiprocessor(&occS, sinkhorn_coop<_Float16>, 256, 0);
    long sCap = (long)occS * numCU;
    int sGrid = (int)(sCap < 1024 ? sCap : 1024);
    if (sGrid < 1) sGrid = 1;
    void* coopArgs[] = {(void*)&Kh, (void*)&u, (void*)&v, (void*)&s,
                        (void*)&errAcc, (void*)&notconv};
    hipLaunchCooperativeKernel(reinterpret_cast<void*>(sinkhorn_coop<_Float16>),
                               dim3(sGrid), dim3(256), coopArgs, 0, stream);
    final_kernel<_Float16><<<dim3(CBLK, 64), 256, 0, stream>>>(Kh, u, v, out, partials, notconv);
    finish_kernel<<<1, 256, 0, stream>>>(partials, out, NPART, notconv);
  } else {
    sumsq_kernel<<<N_T, 256, 0, stream>>>(x, xx, N_T);
    sumsq_kernel<<<M_V, 256, 0, stream>>>(y, yy, M_V);
    bool k_in_ws = ((wp + 512) + kfbytes) <= wend;
    float* Kmat = k_in_ws ? (float*)alloc(kfbytes) : out + 1;
    gemm_k_kernel<<<dim3((M_V + BN - 1) / BN, N_T / BM), 256, 0, stream>>>(x, y, xx, yy, Kmat);
    set1_kernel<<<1, 1, 0, stream>>>(notconv);
    int occS = 0;
    hipOccupancyMaxActiveBlocksPerMultiprocessor(&occS, sinkhorn_coop<float>, 256, 0);
    long sCap = (long)occS * numCU;
    int sGrid = (int)(sCap < 1024 ? sCap : 1024);
    if (sGrid < 1) sGrid = 1;
    void* coopArgs[] = {(void*)&Kmat, (void*)&u, (void*)&v, (void*)&s,
                        (void*)&errAcc, (void*)&notconv};
    hipLaunchCooperativeKernel(reinterpret_cast<void*>(sinkhorn_coop<float>),
                               dim3(sGrid), dim3(256), coopArgs, 0, stream);
    final_kernel<float><<<dim3(CBLK, 64), 256, 0, stream>>>(Kmat, u, v, out, partials, notconv);
    finish_kernel<<<1, 256, 0, stream>>>(partials, out, NPART, notconv);
  }
}